// Round 14
// baseline (26.799 us; speedup 1.0000x reference)
//
#include <hip/hip_runtime.h>
#include <hip/hip_bf16.h>
#include <math.h>

#define NB 8
#define NL 128
#define D_ATOM 256
#define DH 32       // d_hid
#define DAB 64      // 2*d_hid
#define K1 21
#define K2 30
#define KT 51       // K1+K2
#define ROWS (NB*NL) // 1024
#define LN_EPS 1e-5f

#define OUT1_ROW (NL*K1)      // 2688 floats
#define OUT2_ROW (NL*K2)      // 3840 floats
#define STAGE_N  (OUT1_ROW + OUT2_ROW) // 6528 floats
#define WCAT 1632             // 672 + 960 els per c

typedef __attribute__((ext_vector_type(8))) short bf16x8;
typedef __attribute__((ext_vector_type(4))) float f32x4;

__device__ __forceinline__ unsigned short f2bf(float x) {
    __hip_bfloat16 h = __float2bfloat16(x);
    return *reinterpret_cast<unsigned short*>(&h);
}

// ---------------- Kernel 1: skinny LN (blocks 0..511) + Wlin2 prep (512..575)
// LN: 1 wave per block, 2 rows; GEMV direct from L2 (no LDS, no barriers).
//   Identical FMA order / LN math / output layouts to verified R13 kernel.
// Wlin2 prep: verified R13 packing, re-indexed to 64 x 1-wave blocks.
__global__ __launch_bounds__(64) void ln_wprep_kernel(
    const float* __restrict__ z, const float* __restrict__ W_in,
    const float* __restrict__ b_in, const float* __restrict__ ln_g,
    const float* __restrict__ ln_b, const float* __restrict__ W1,
    const float* __restrict__ W2, float* __restrict__ a_ws,
    unsigned short* __restrict__ bbf, unsigned short* __restrict__ Wlin2)
{
    const int t = threadIdx.x;          // 0..63

    if (blockIdx.x >= 512) {
        // ---- Wlin2 prep: 64 blocks * 64 thr * 2 = 8192 uint4 entries ----
        const int base = ((int)blockIdx.x - 512) * 128;
        #pragma unroll
        for (int e = 0; e < 2; ++e) {
            int p  = base + e * 64 + t;         // 0..8191
            int c  = p >> 8, t2 = p & 255;
            unsigned short v[8];
            #pragma unroll
            for (int s = 0; s < 8; ++s) {
                int o = s * 256 + t2;
                float val = 0.f;
                if (o < 672)       val = W1[c * 672 + o];
                else if (o < WCAT) val = W2[c * 960 + (o - 672)];
                v[s] = f2bf(val);
            }
            uint4 wq;
            wq.x = (unsigned)v[0] | ((unsigned)v[1] << 16);
            wq.y = (unsigned)v[2] | ((unsigned)v[3] << 16);
            wq.z = (unsigned)v[4] | ((unsigned)v[5] << 16);
            wq.w = (unsigned)v[6] | ((unsigned)v[7] << 16);
            ((uint4*)Wlin2)[p] = wq;
        }
        return;
    }

    // ---- LN: rows r0, r0+1 ----
    const int r0 = blockIdx.x * 2;
    const int j  = t;
    const float* z0 = z + (size_t)r0 * D_ATOM;
    const float* z1 = z0 + D_ATOM;

    float acc0 = b_in[j], acc1 = acc0;
    #pragma unroll 8
    for (int c = 0; c < D_ATOM; ++c) {
        float wv = W_in[c * DAB + j];       // 256B coalesced, L2-hot
        acc0 = fmaf(z0[c], wv, acc0);       // z reads are wave-uniform -> SMEM
        acc1 = fmaf(z1[c], wv, acc1);
    }

    float g0 = 0.5f * acc0 * (1.0f + erff(acc0 * 0.70710678118654752f));
    float g1 = 0.5f * acc1 * (1.0f + erff(acc1 * 0.70710678118654752f));

    float s0 = g0, sq0 = g0 * g0, s1 = g1, sq1 = g1 * g1;
    #pragma unroll
    for (int msk = 1; msk < 64; msk <<= 1) {
        s0  += __shfl_xor(s0,  msk, 64);
        sq0 += __shfl_xor(sq0, msk, 64);
        s1  += __shfl_xor(s1,  msk, 64);
        sq1 += __shfl_xor(sq1, msk, 64);
    }
    float mu0  = s0  * (1.0f / 64.0f);
    float var0 = sq0 * (1.0f / 64.0f) - mu0 * mu0;
    float mu1  = s1  * (1.0f / 64.0f);
    float var1 = sq1 * (1.0f / 64.0f) - mu1 * mu1;
    float gg = ln_g[j], bb = ln_b[j];
    float y0 = (g0 - mu0) * rsqrtf(var0 + LN_EPS) * gg + bb;
    float y1 = (g1 - mu1) * rsqrtf(var1 + LN_EPS) * gg + bb;

    #pragma unroll
    for (int rr = 0; rr < 2; ++rr) {
        const int row = r0 + rr;
        float y = rr ? y1 : y0;
        if (j < DH) {
            a_ws[row * DH + j] = y;          // f32, coalesced
        } else {
            const int d = j - DH, m = row & 127, batch = row >> 7;
            bbf[batch * 4096 + ((m >> 4) << 9) +
                ((((m & 15) | ((d >> 3) << 4)) << 3) | (d & 7))] = f2bf(y);
        }
    }
}

// ---------------- Kernel 2: pair product (byte-identical to R13 — best) -----
// 2 rows per block, 512 blocks, 34.6 KB LDS -> 4 blocks/CU (16 waves/CU).
__global__ __launch_bounds__(256, 4) void pair_kernel(
    const float* __restrict__ a_ws, const unsigned short* __restrict__ bbf,
    const unsigned short* __restrict__ Wlin2, const float* __restrict__ b1v,
    const float* __restrict__ b2v, float* __restrict__ out)
{
    const int row0  = blockIdx.x * 2;
    const int batch = row0 >> 7;
    const int t     = threadIdx.x;
    const int w  = t >> 6, l = t & 63;
    const int lg = l >> 4, li = l & 15;

    __shared__ unsigned short Tf[2 * 4 * 64 * 8];    // 8 KB
    __shared__ __align__(16) float stg[STAGE_N];     // 25.5 KB (one row)
    __shared__ float al[2][DH];

    #pragma unroll
    for (int s = 0; s < 8; ++s)
        ((unsigned int*)Tf)[t + s * 256] = 0u;       // pads k=51..63 stay 0
    if (t < 2 * DH) al[t >> 5][t & 31] = a_ws[row0 * DH + t];
    __syncthreads();

    // ---- phase 1: T GEMV (uint4-packed Wlin2) ----
    {
        float tacc0[7], tacc1[7];
        int fidx[7];
        bool val[7];
        #pragma unroll
        for (int s = 0; s < 7; ++s) {
            int o = t + s * 256;
            val[s] = (o < WCAT);
            int oo = val[s] ? o : 0;
            int d, k;
            if (oo < 672) { d = oo / 21; k = oo % 21; }
            else { int o2 = oo - 672; d = o2 / 30; k = 21 + o2 % 30; }
            fidx[s] = (((k >> 4) * 64 + ((k & 15) | ((d >> 3) << 4))) << 3) | (d & 7);
            tacc0[s] = 0.f; tacc1[s] = 0.f;
        }
        const uint4* wbase = ((const uint4*)Wlin2) + t;
        #pragma unroll 4
        for (int c = 0; c < DH; ++c) {
            float ac0 = al[0][c], ac1 = al[1][c];
            uint4 wq = wbase[c * 256];
            float wv[7];
            wv[0] = __uint_as_float(wq.x << 16);
            wv[1] = __uint_as_float(wq.x & 0xffff0000u);
            wv[2] = __uint_as_float(wq.y << 16);
            wv[3] = __uint_as_float(wq.y & 0xffff0000u);
            wv[4] = __uint_as_float(wq.z << 16);
            wv[5] = __uint_as_float(wq.z & 0xffff0000u);
            wv[6] = __uint_as_float(wq.w << 16);
            #pragma unroll
            for (int s = 0; s < 7; ++s) {
                tacc0[s] = fmaf(ac0, wv[s], tacc0[s]);
                tacc1[s] = fmaf(ac1, wv[s], tacc1[s]);
            }
        }
        #pragma unroll
        for (int s = 0; s < 7; ++s) {
            if (val[s]) {
                Tf[fidx[s]]        = f2bf(tacc0[s]);
                Tf[2048 + fidx[s]] = f2bf(tacc1[s]);
            }
        }
    }
    __syncthreads();

    // ---- phase 2/3: per-row MFMA + stage + copyout (verified) ----
    const int r  = w >> 1;            // wave's row within pair
    const int mh = w & 1;             // m-half

    bf16x8 afr[4], bfr[4];
    #pragma unroll
    for (int i = 0; i < 4; ++i)
        afr[i] = ((const bf16x8*)bbf)[batch * 512 + (mh * 4 + i) * 64 + l];
    #pragma unroll
    for (int kt = 0; kt < 4; ++kt)
        bfr[kt] = ((const bf16x8*)Tf)[(r * 4 + kt) * 64 + l];

    float bias[4];
    #pragma unroll
    for (int kt = 0; kt < 4; ++kt) {
        int k = kt * 16 + li;
        bias[kt] = (k < K1) ? b1v[k] : (k < KT ? b2v[k - K1] : 0.f);
    }

    #pragma unroll
    for (int rr = 0; rr < 2; ++rr) {
        if (r == rr) {
            #pragma unroll
            for (int i = 0; i < 4; ++i) {
                const int mbase = (mh * 4 + i) * 16 + lg * 4;
                #pragma unroll
                for (int kt = 0; kt < 4; ++kt) {
                    f32x4 acc = __builtin_amdgcn_mfma_f32_16x16x32_bf16(
                        afr[i], bfr[kt], (f32x4){0.f, 0.f, 0.f, 0.f}, 0, 0, 0);
                    const int k = kt * 16 + li;
                    if (k < K1) {
                        #pragma unroll
                        for (int q = 0; q < 4; ++q)
                            stg[(mbase + q) * K1 + k] = acc[q] + bias[kt];
                    } else if (k < KT) {
                        #pragma unroll
                        for (int q = 0; q < 4; ++q)
                            stg[OUT1_ROW + (mbase + q) * K2 + (k - K1)] = acc[q] + bias[kt];
                    }
                }
            }
        }
        __syncthreads();

        const int row = row0 + rr;
        float* o1 = out + (size_t)row * OUT1_ROW;
        float* o2 = out + (size_t)ROWS * OUT1_ROW + (size_t)row * OUT2_ROW;
        const float4* s1 = (const float4*)stg;
        const float4* s2 = (const float4*)(stg + OUT1_ROW);
        for (int i4 = t; i4 < OUT1_ROW / 4; i4 += 256)
            ((float4*)o1)[i4] = s1[i4];
        for (int i4 = t; i4 < OUT2_ROW / 4; i4 += 256)
            ((float4*)o2)[i4] = s2[i4];
        if (rr == 0) __syncthreads();   // stg reused by row 1
    }
}

extern "C" void kernel_launch(void* const* d_in, const int* in_sizes, int n_in,
                              void* d_out, int out_size, void* d_ws, size_t ws_size,
                              hipStream_t stream) {
    const float* z    = (const float*)d_in[0];
    const float* W_in = (const float*)d_in[1];
    const float* b_in = (const float*)d_in[2];
    const float* ln_g = (const float*)d_in[3];
    const float* ln_b = (const float*)d_in[4];
    const float* W1   = (const float*)d_in[5];
    const float* b1   = (const float*)d_in[6];
    const float* W2   = (const float*)d_in[7];
    const float* b2   = (const float*)d_in[8];
    float* out = (float*)d_out;

    float*          a_ws  = (float*)d_ws;                    // 32768 f32 (128 KB)
    unsigned short* bbf   = (unsigned short*)(a_ws + 32768); // 32768 hw (64 KB)
    unsigned short* Wlin2 = bbf + 32768;                     // 65536 hw (128 KB)

    ln_wprep_kernel<<<576, 64, 0, stream>>>(z, W_in, b_in, ln_g, ln_b,
                                            W1, W2, a_ws, bbf, Wlin2);
    pair_kernel<<<ROWS / 2, 256, 0, stream>>>(a_ws, bbf, Wlin2, b1, b2, out);
}

// Round 15
// 24.322 us; speedup vs baseline: 1.1018x; 1.1018x over previous
//
#include <hip/hip_runtime.h>
#include <hip/hip_bf16.h>
#include <math.h>

#define NB 8
#define NL 128
#define D_ATOM 256
#define DH 32       // d_hid
#define DAB 64      // 2*d_hid
#define K1 21
#define K2 30
#define KT 51       // K1+K2
#define ROWS (NB*NL) // 1024
#define LN_EPS 1e-5f

#define OUT1_ROW (NL*K1)      // 2688 floats
#define OUT2_ROW (NL*K2)      // 3840 floats
#define WCAT 1632             // 672 + 960 els per c

typedef __attribute__((ext_vector_type(8))) short bf16x8;
typedef __attribute__((ext_vector_type(4))) float f32x4;

__device__ __forceinline__ unsigned short f2bf(float x) {
    __hip_bfloat16 h = __float2bfloat16(x);
    return *reinterpret_cast<unsigned short*>(&h);
}

// ---------------- Kernel 1: LN (R13-verified) + folded Wlin2 prep ------------
// 256 blocks x 256 thr. Each block: 4 LN rows (W_in staged in LDS), then
// threads t<32 pack this block's 32 uint4 Wlin2 entries (verified packing).
__global__ __launch_bounds__(256) void ln_wprep_kernel(
    const float* __restrict__ z, const float* __restrict__ W_in,
    const float* __restrict__ b_in, const float* __restrict__ ln_g,
    const float* __restrict__ ln_b, const float* __restrict__ W1,
    const float* __restrict__ W2, float* __restrict__ a_ws,
    unsigned short* __restrict__ bbf, unsigned short* __restrict__ Wlin2)
{
    __shared__ float Wl[D_ATOM * DAB];   // 64 KB
    __shared__ float zl[4][D_ATOM];      // 4 KB
    const int t = threadIdx.x;
    const int w = t >> 6, j = t & 63;
    const int row0 = blockIdx.x * 4;

    #pragma unroll
    for (int s = 0; s < 16; ++s) {
        int i4 = t + s * 256;
        ((float4*)Wl)[i4] = ((const float4*)W_in)[i4];
    }
    ((float4*)zl)[t] = ((const float4*)(z + (size_t)row0 * D_ATOM))[t];
    __syncthreads();

    float acc = b_in[j];
    #pragma unroll 8
    for (int i = 0; i < D_ATOM; ++i)
        acc = fmaf(zl[w][i], Wl[i * DAB + j], acc);

    float g = 0.5f * acc * (1.0f + erff(acc * 0.70710678118654752f));

    float s = g, sq = g * g;
    #pragma unroll
    for (int msk = 1; msk < 64; msk <<= 1) {
        s  += __shfl_xor(s,  msk, 64);
        sq += __shfl_xor(sq, msk, 64);
    }
    float mu  = s  * (1.0f / 64.0f);
    float var = sq * (1.0f / 64.0f) - mu * mu;
    float y = (g - mu) * rsqrtf(var + LN_EPS) * ln_g[j] + ln_b[j];

    const int row = row0 + w;
    if (j < DH) {
        a_ws[row * DH + j] = y;          // f32, coalesced
    } else {
        const int d = j - DH, m = row & 127, batch = row >> 7;
        bbf[batch * 4096 + ((m >> 4) << 9) +
            ((((m & 15) | ((d >> 3) << 4)) << 3) | (d & 7))] = f2bf(y);
    }

    // ---- folded Wlin2 prep: 256 blocks x 32 entries = 8192 uint4 ----
    if (t < 32) {
        int p  = (int)blockIdx.x * 32 + t;      // 0..8191
        int c  = p >> 8, t2 = p & 255;
        unsigned short v[8];
        #pragma unroll
        for (int s2 = 0; s2 < 8; ++s2) {
            int o = s2 * 256 + t2;
            float val = 0.f;
            if (o < 672)       val = W1[c * 672 + o];
            else if (o < WCAT) val = W2[c * 960 + (o - 672)];
            v[s2] = f2bf(val);
        }
        uint4 wq;
        wq.x = (unsigned)v[0] | ((unsigned)v[1] << 16);
        wq.y = (unsigned)v[2] | ((unsigned)v[3] << 16);
        wq.z = (unsigned)v[4] | ((unsigned)v[5] << 16);
        wq.w = (unsigned)v[6] | ((unsigned)v[7] << 16);
        ((uint4*)Wlin2)[p] = wq;
    }
}

// ---------------- Kernel 2: pair product (direct MFMA->global stores) -------
// 2 rows per block, 512 blocks. LDS = Tf 8KB + al only.
// Phase 1: T GEMV (uint4-packed Wlin2) — verified R13.
// Phase 2: 16 MFMA/wave, store C fragments DIRECTLY to out (4-segment
//          wave-stores; indices byte-identical to the verified stg writes).
__global__ __launch_bounds__(256, 4) void pair_kernel(
    const float* __restrict__ a_ws, const unsigned short* __restrict__ bbf,
    const unsigned short* __restrict__ Wlin2, const float* __restrict__ b1v,
    const float* __restrict__ b2v, float* __restrict__ out)
{
    const int row0  = blockIdx.x * 2;
    const int batch = row0 >> 7;
    const int t     = threadIdx.x;
    const int w  = t >> 6, l = t & 63;
    const int lg = l >> 4, li = l & 15;

    __shared__ unsigned short Tf[2 * 4 * 64 * 8];    // 8 KB
    __shared__ float al[2][DH];

    #pragma unroll
    for (int s = 0; s < 8; ++s)
        ((unsigned int*)Tf)[t + s * 256] = 0u;       // pads k=51..63 stay 0
    if (t < 2 * DH) al[t >> 5][t & 31] = a_ws[row0 * DH + t];
    __syncthreads();

    // ---- phase 1: T GEMV (uint4-packed Wlin2; verified R13) ----
    {
        float tacc0[7], tacc1[7];
        int fidx[7];
        bool val[7];
        #pragma unroll
        for (int s = 0; s < 7; ++s) {
            int o = t + s * 256;
            val[s] = (o < WCAT);
            int oo = val[s] ? o : 0;
            int d, k;
            if (oo < 672) { d = oo / 21; k = oo % 21; }
            else { int o2 = oo - 672; d = o2 / 30; k = 21 + o2 % 30; }
            fidx[s] = (((k >> 4) * 64 + ((k & 15) | ((d >> 3) << 4))) << 3) | (d & 7);
            tacc0[s] = 0.f; tacc1[s] = 0.f;
        }
        const uint4* wbase = ((const uint4*)Wlin2) + t;
        #pragma unroll 4
        for (int c = 0; c < DH; ++c) {
            float ac0 = al[0][c], ac1 = al[1][c];
            uint4 wq = wbase[c * 256];
            float wv[7];
            wv[0] = __uint_as_float(wq.x << 16);
            wv[1] = __uint_as_float(wq.x & 0xffff0000u);
            wv[2] = __uint_as_float(wq.y << 16);
            wv[3] = __uint_as_float(wq.y & 0xffff0000u);
            wv[4] = __uint_as_float(wq.z << 16);
            wv[5] = __uint_as_float(wq.z & 0xffff0000u);
            wv[6] = __uint_as_float(wq.w << 16);
            #pragma unroll
            for (int s = 0; s < 7; ++s) {
                tacc0[s] = fmaf(ac0, wv[s], tacc0[s]);
                tacc1[s] = fmaf(ac1, wv[s], tacc1[s]);
            }
        }
        #pragma unroll
        for (int s = 0; s < 7; ++s) {
            if (val[s]) {
                Tf[fidx[s]]        = f2bf(tacc0[s]);
                Tf[2048 + fidx[s]] = f2bf(tacc1[s]);
            }
        }
    }
    __syncthreads();

    // ---- phase 2: MFMA + direct global stores (indices == verified stg) ----
    const int r  = w >> 1;            // wave's row within pair
    const int mh = w & 1;             // m-half

    bf16x8 afr[4], bfr[4];
    #pragma unroll
    for (int i = 0; i < 4; ++i)
        afr[i] = ((const bf16x8*)bbf)[batch * 512 + (mh * 4 + i) * 64 + l];
    #pragma unroll
    for (int kt = 0; kt < 4; ++kt)
        bfr[kt] = ((const bf16x8*)Tf)[(r * 4 + kt) * 64 + l];

    float bias[4];
    #pragma unroll
    for (int kt = 0; kt < 4; ++kt) {
        int k = kt * 16 + li;
        bias[kt] = (k < K1) ? b1v[k] : (k < KT ? b2v[k - K1] : 0.f);
    }

    const int row = row0 + r;
    float* o1 = out + (size_t)row * OUT1_ROW;
    float* o2 = out + (size_t)ROWS * OUT1_ROW + (size_t)row * OUT2_ROW;

    #pragma unroll
    for (int i = 0; i < 4; ++i) {
        const int mbase = (mh * 4 + i) * 16 + lg * 4;
        #pragma unroll
        for (int kt = 0; kt < 4; ++kt) {
            f32x4 acc = __builtin_amdgcn_mfma_f32_16x16x32_bf16(
                afr[i], bfr[kt], (f32x4){0.f, 0.f, 0.f, 0.f}, 0, 0, 0);
            const int k = kt * 16 + li;
            if (k < K1) {
                #pragma unroll
                for (int q = 0; q < 4; ++q)
                    o1[(mbase + q) * K1 + k] = acc[q] + bias[kt];
            } else if (k < KT) {
                #pragma unroll
                for (int q = 0; q < 4; ++q)
                    o2[(mbase + q) * K2 + (k - K1)] = acc[q] + bias[kt];
            }
        }
    }
}

extern "C" void kernel_launch(void* const* d_in, const int* in_sizes, int n_in,
                              void* d_out, int out_size, void* d_ws, size_t ws_size,
                              hipStream_t stream) {
    const float* z    = (const float*)d_in[0];
    const float* W_in = (const float*)d_in[1];
    const float* b_in = (const float*)d_in[2];
    const float* ln_g = (const float*)d_in[3];
    const float* ln_b = (const float*)d_in[4];
    const float* W1   = (const float*)d_in[5];
    const float* b1   = (const float*)d_in[6];
    const float* W2   = (const float*)d_in[7];
    const float* b2   = (const float*)d_in[8];
    float* out = (float*)d_out;

    float*          a_ws  = (float*)d_ws;                    // 32768 f32 (128 KB)
    unsigned short* bbf   = (unsigned short*)(a_ws + 32768); // 32768 hw (64 KB)
    unsigned short* Wlin2 = bbf + 32768;                     // 65536 hw (128 KB)

    ln_wprep_kernel<<<256, 256, 0, stream>>>(z, W_in, b_in, ln_g, ln_b,
                                             W1, W2, a_ws, bbf, Wlin2);
    pair_kernel<<<ROWS / 2, 256, 0, stream>>>(a_ws, bbf, Wlin2, b1, b2, out);
}

// Round 16
// 24.077 us; speedup vs baseline: 1.1130x; 1.0102x over previous
//
#include <hip/hip_runtime.h>
#include <hip/hip_bf16.h>
#include <math.h>

#define NB 8
#define NL 128
#define D_ATOM 256
#define DH 32       // d_hid
#define DAB 64      // 2*d_hid
#define K1 21
#define K2 30
#define KT 51       // K1+K2
#define ROWS (NB*NL) // 1024
#define LN_EPS 1e-5f

#define OUT1_ROW (NL*K1)      // 2688 floats
#define OUT2_ROW (NL*K2)      // 3840 floats
#define STAGE_N  (OUT1_ROW + OUT2_ROW) // 6528 floats
#define WCAT 1632             // 672 + 960 els per c

typedef __attribute__((ext_vector_type(8))) short bf16x8;
typedef __attribute__((ext_vector_type(4))) float f32x4;

__device__ __forceinline__ unsigned short f2bf(float x) {
    __hip_bfloat16 h = __float2bfloat16(x);
    return *reinterpret_cast<unsigned short*>(&h);
}

// ---------------- Kernel 1: LN (blocks 0..255) + Wlin2 prep (256..271) ------
// Byte-identical to R13 (best verified).
__global__ __launch_bounds__(256) void ln_wprep_kernel(
    const float* __restrict__ z, const float* __restrict__ W_in,
    const float* __restrict__ b_in, const float* __restrict__ ln_g,
    const float* __restrict__ ln_b, const float* __restrict__ W1,
    const float* __restrict__ W2, float* __restrict__ a_ws,
    unsigned short* __restrict__ bbf, unsigned short* __restrict__ Wlin2)
{
    const int t = threadIdx.x;

    if (blockIdx.x >= 256) {
        const int base = ((int)blockIdx.x - 256) * 512;
        #pragma unroll
        for (int e = 0; e < 2; ++e) {
            int p  = base + e * 256 + t;        // 0..8191
            int c  = p >> 8, t2 = p & 255;
            unsigned short v[8];
            #pragma unroll
            for (int s = 0; s < 8; ++s) {
                int o = s * 256 + t2;
                float val = 0.f;
                if (o < 672)       val = W1[c * 672 + o];
                else if (o < WCAT) val = W2[c * 960 + (o - 672)];
                v[s] = f2bf(val);
            }
            uint4 wq;
            wq.x = (unsigned)v[0] | ((unsigned)v[1] << 16);
            wq.y = (unsigned)v[2] | ((unsigned)v[3] << 16);
            wq.z = (unsigned)v[4] | ((unsigned)v[5] << 16);
            wq.w = (unsigned)v[6] | ((unsigned)v[7] << 16);
            ((uint4*)Wlin2)[p] = wq;
        }
        return;
    }

    __shared__ float Wl[D_ATOM * DAB];   // 64 KB
    __shared__ float zl[4][D_ATOM];      // 4 KB
    const int w = t >> 6, j = t & 63;
    const int row0 = blockIdx.x * 4;

    #pragma unroll
    for (int s = 0; s < 16; ++s) {
        int i4 = t + s * 256;
        ((float4*)Wl)[i4] = ((const float4*)W_in)[i4];
    }
    ((float4*)zl)[t] = ((const float4*)(z + (size_t)row0 * D_ATOM))[t];
    __syncthreads();

    float acc = b_in[j];
    #pragma unroll 8
    for (int i = 0; i < D_ATOM; ++i)
        acc = fmaf(zl[w][i], Wl[i * DAB + j], acc);

    float g = 0.5f * acc * (1.0f + erff(acc * 0.70710678118654752f));

    float s = g, sq = g * g;
    #pragma unroll
    for (int msk = 1; msk < 64; msk <<= 1) {
        s  += __shfl_xor(s,  msk, 64);
        sq += __shfl_xor(sq, msk, 64);
    }
    float mu  = s  * (1.0f / 64.0f);
    float var = sq * (1.0f / 64.0f) - mu * mu;
    float y = (g - mu) * rsqrtf(var + LN_EPS) * ln_g[j] + ln_b[j];

    const int row = row0 + w;
    if (j < DH) {
        a_ws[row * DH + j] = y;          // f32, coalesced
    } else {
        const int d = j - DH, m = row & 127, batch = row >> 7;
        bbf[batch * 4096 + ((m >> 4) << 9) +
            ((((m & 15) | ((d >> 3) << 4)) << 3) | (d & 7))] = f2bf(y);
    }
}

// ---------------- Kernel 2: pair product (R13 minus init/barrier/al) --------
// 2 rows per block, 512 blocks. LDS = Tf 8KB + stg 25.5KB.
// a read via block-uniform scalar loads (SGPR); no Tf zero-init (kt=3 pad
// lanes masked in-register, R9-verified); one barrier fewer than R13.
__global__ __launch_bounds__(256, 4) void pair_kernel(
    const float* __restrict__ a_ws, const unsigned short* __restrict__ bbf,
    const unsigned short* __restrict__ Wlin2, const float* __restrict__ b1v,
    const float* __restrict__ b2v, float* __restrict__ out)
{
    const int row0  = blockIdx.x * 2;
    const int batch = row0 >> 7;
    const int t     = threadIdx.x;
    const int w  = t >> 6, l = t & 63;
    const int lg = l >> 4, li = l & 15;

    __shared__ unsigned short Tf[2 * 4 * 64 * 8];    // 8 KB
    __shared__ __align__(16) float stg[STAGE_N];     // 25.5 KB (one row)

    const float* ar = a_ws + (size_t)row0 * DH;      // block-uniform -> s_load

    // ---- phase 1: T GEMV (uint4-packed Wlin2; verified R13 math) ----
    {
        float tacc0[7], tacc1[7];
        int fidx[7];
        bool val[7];
        #pragma unroll
        for (int s = 0; s < 7; ++s) {
            int o = t + s * 256;
            val[s] = (o < WCAT);
            int oo = val[s] ? o : 0;
            int d, k;
            if (oo < 672) { d = oo / 21; k = oo % 21; }
            else { int o2 = oo - 672; d = o2 / 30; k = 21 + o2 % 30; }
            fidx[s] = (((k >> 4) * 64 + ((k & 15) | ((d >> 3) << 4))) << 3) | (d & 7);
            tacc0[s] = 0.f; tacc1[s] = 0.f;
        }
        const uint4* wbase = ((const uint4*)Wlin2) + t;
        #pragma unroll 4
        for (int c = 0; c < DH; ++c) {
            float ac0 = ar[c], ac1 = ar[DH + c];     // SGPR operands
            uint4 wq = wbase[c * 256];
            float wv[7];
            wv[0] = __uint_as_float(wq.x << 16);
            wv[1] = __uint_as_float(wq.x & 0xffff0000u);
            wv[2] = __uint_as_float(wq.y << 16);
            wv[3] = __uint_as_float(wq.y & 0xffff0000u);
            wv[4] = __uint_as_float(wq.z << 16);
            wv[5] = __uint_as_float(wq.z & 0xffff0000u);
            wv[6] = __uint_as_float(wq.w << 16);
            #pragma unroll
            for (int s = 0; s < 7; ++s) {
                tacc0[s] = fmaf(ac0, wv[s], tacc0[s]);
                tacc1[s] = fmaf(ac1, wv[s], tacc1[s]);
            }
        }
        #pragma unroll
        for (int s = 0; s < 7; ++s) {
            if (val[s]) {
                Tf[fidx[s]]        = f2bf(tacc0[s]);
                Tf[2048 + fidx[s]] = f2bf(tacc1[s]);
            }
        }
    }
    __syncthreads();

    // ---- phase 2/3: per-row MFMA + stage + copyout (verified R13) ----
    const int r  = w >> 1;            // wave's row within pair
    const int mh = w & 1;             // m-half

    bf16x8 afr[4], bfr[4];
    #pragma unroll
    for (int i = 0; i < 4; ++i)
        afr[i] = ((const bf16x8*)bbf)[batch * 512 + (mh * 4 + i) * 64 + l];
    #pragma unroll
    for (int kt = 0; kt < 4; ++kt)
        bfr[kt] = ((const bf16x8*)Tf)[(r * 4 + kt) * 64 + l];

    // kt=3 tile: lanes with k = 48+li >= 51 hold unwritten LDS -> zero (R9-verified)
    if (li >= 3) {
        bf16x8 zz = {0, 0, 0, 0, 0, 0, 0, 0};
        bfr[3] = zz;
    }

    float bias[4];
    #pragma unroll
    for (int kt = 0; kt < 4; ++kt) {
        int k = kt * 16 + li;
        bias[kt] = (k < K1) ? b1v[k] : (k < KT ? b2v[k - K1] : 0.f);
    }

    #pragma unroll
    for (int rr = 0; rr < 2; ++rr) {
        if (r == rr) {
            #pragma unroll
            for (int i = 0; i < 4; ++i) {
                const int mbase = (mh * 4 + i) * 16 + lg * 4;
                #pragma unroll
                for (int kt = 0; kt < 4; ++kt) {
                    f32x4 acc = __builtin_amdgcn_mfma_f32_16x16x32_bf16(
                        afr[i], bfr[kt], (f32x4){0.f, 0.f, 0.f, 0.f}, 0, 0, 0);
                    const int k = kt * 16 + li;
                    if (k < K1) {
                        #pragma unroll
                        for (int q = 0; q < 4; ++q)
                            stg[(mbase + q) * K1 + k] = acc[q] + bias[kt];
                    } else if (k < KT) {
                        #pragma unroll
                        for (int q = 0; q < 4; ++q)
                            stg[OUT1_ROW + (mbase + q) * K2 + (k - K1)] = acc[q] + bias[kt];
                    }
                }
            }
        }
        __syncthreads();

        const int row = row0 + rr;
        float* o1 = out + (size_t)row * OUT1_ROW;
        float* o2 = out + (size_t)ROWS * OUT1_ROW + (size_t)row * OUT2_ROW;
        const float4* s1 = (const float4*)stg;
        const float4* s2 = (const float4*)(stg + OUT1_ROW);
        for (int i4 = t; i4 < OUT1_ROW / 4; i4 += 256)
            ((float4*)o1)[i4] = s1[i4];
        for (int i4 = t; i4 < OUT2_ROW / 4; i4 += 256)
            ((float4*)o2)[i4] = s2[i4];
        if (rr == 0) __syncthreads();   // stg reused by row 1
    }
}

extern "C" void kernel_launch(void* const* d_in, const int* in_sizes, int n_in,
                              void* d_out, int out_size, void* d_ws, size_t ws_size,
                              hipStream_t stream) {
    const float* z    = (const float*)d_in[0];
    const float* W_in = (const float*)d_in[1];
    const float* b_in = (const float*)d_in[2];
    const float* ln_g = (const float*)d_in[3];
    const float* ln_b = (const float*)d_in[4];
    const float* W1   = (const float*)d_in[5];
    const float* b1   = (const float*)d_in[6];
    const float* W2   = (const float*)d_in[7];
    const float* b2   = (const float*)d_in[8];
    float* out = (float*)d_out;

    float*          a_ws  = (float*)d_ws;                    // 32768 f32 (128 KB)
    unsigned short* bbf   = (unsigned short*)(a_ws + 32768); // 32768 hw (64 KB)
    unsigned short* Wlin2 = bbf + 32768;                     // 65536 hw (128 KB)

    ln_wprep_kernel<<<272, 256, 0, stream>>>(z, W_in, b_in, ln_g, ln_b,
                                             W1, W2, a_ws, bbf, Wlin2);
    pair_kernel<<<ROWS / 2, 256, 0, stream>>>(a_ws, bbf, Wlin2, b1, b2, out);
}

// Round 17
// 22.943 us; speedup vs baseline: 1.1681x; 1.0494x over previous
//
#include <hip/hip_runtime.h>
#include <hip/hip_bf16.h>
#include <math.h>

#define NB 8
#define NL 128
#define D_ATOM 256
#define DH 32       // d_hid
#define DAB 64      // 2*d_hid
#define K1 21
#define K2 30
#define KT 51       // K1+K2
#define ROWS (NB*NL) // 1024
#define LN_EPS 1e-5f

#define OUT1_ROW (NL*K1)      // 2688 floats
#define OUT2_ROW (NL*K2)      // 3840 floats
#define STAGE_N  (OUT1_ROW + OUT2_ROW) // 6528 floats
#define WCAT 1632             // 672 + 960 els per c

typedef __attribute__((ext_vector_type(8))) short bf16x8;
typedef __attribute__((ext_vector_type(4))) float f32x4;

__device__ __forceinline__ unsigned short f2bf(float x) {
    __hip_bfloat16 h = __float2bfloat16(x);
    return *reinterpret_cast<unsigned short*>(&h);
}

// ---------------- Kernel 1: LN + folded Wlin2 prep (R15-verified) ------------
// 256 blocks x 256 thr, balanced: each block does 4 LN rows (W_in in LDS) and
// its threads t<32 pack 32 uint4 Wlin2 entries (no straggler blocks).
__global__ __launch_bounds__(256) void ln_wprep_kernel(
    const float* __restrict__ z, const float* __restrict__ W_in,
    const float* __restrict__ b_in, const float* __restrict__ ln_g,
    const float* __restrict__ ln_b, const float* __restrict__ W1,
    const float* __restrict__ W2, float* __restrict__ a_ws,
    unsigned short* __restrict__ bbf, unsigned short* __restrict__ Wlin2)
{
    __shared__ float Wl[D_ATOM * DAB];   // 64 KB
    __shared__ float zl[4][D_ATOM];      // 4 KB
    const int t = threadIdx.x;
    const int w = t >> 6, j = t & 63;
    const int row0 = blockIdx.x * 4;

    #pragma unroll
    for (int s = 0; s < 16; ++s) {
        int i4 = t + s * 256;
        ((float4*)Wl)[i4] = ((const float4*)W_in)[i4];
    }
    ((float4*)zl)[t] = ((const float4*)(z + (size_t)row0 * D_ATOM))[t];
    __syncthreads();

    float acc = b_in[j];
    #pragma unroll 8
    for (int i = 0; i < D_ATOM; ++i)
        acc = fmaf(zl[w][i], Wl[i * DAB + j], acc);

    float g = 0.5f * acc * (1.0f + erff(acc * 0.70710678118654752f));

    float s = g, sq = g * g;
    #pragma unroll
    for (int msk = 1; msk < 64; msk <<= 1) {
        s  += __shfl_xor(s,  msk, 64);
        sq += __shfl_xor(sq, msk, 64);
    }
    float mu  = s  * (1.0f / 64.0f);
    float var = sq * (1.0f / 64.0f) - mu * mu;
    float y = (g - mu) * rsqrtf(var + LN_EPS) * ln_g[j] + ln_b[j];

    const int row = row0 + w;
    if (j < DH) {
        a_ws[row * DH + j] = y;          // f32, coalesced
    } else {
        const int d = j - DH, m = row & 127, batch = row >> 7;
        bbf[batch * 4096 + ((m >> 4) << 9) +
            ((((m & 15) | ((d >> 3) << 4)) << 3) | (d & 7))] = f2bf(y);
    }

    // ---- folded Wlin2 prep: 256 blocks x 32 entries = 8192 uint4 ----
    if (t < 32) {
        int p  = (int)blockIdx.x * 32 + t;      // 0..8191
        int c  = p >> 8, t2 = p & 255;
        unsigned short v[8];
        #pragma unroll
        for (int s2 = 0; s2 < 8; ++s2) {
            int o = s2 * 256 + t2;
            float val = 0.f;
            if (o < 672)       val = W1[c * 672 + o];
            else if (o < WCAT) val = W2[c * 960 + (o - 672)];
            v[s2] = f2bf(val);
        }
        uint4 wq;
        wq.x = (unsigned)v[0] | ((unsigned)v[1] << 16);
        wq.y = (unsigned)v[2] | ((unsigned)v[3] << 16);
        wq.z = (unsigned)v[4] | ((unsigned)v[5] << 16);
        wq.w = (unsigned)v[6] | ((unsigned)v[7] << 16);
        ((uint4*)Wlin2)[p] = wq;
    }
}

// ---------------- Kernel 2: pair product (byte-identical to R13 — best) -----
// 2 rows per block, 512 blocks, 34.6 KB LDS -> 4 blocks/CU (16 waves/CU).
__global__ __launch_bounds__(256, 4) void pair_kernel(
    const float* __restrict__ a_ws, const unsigned short* __restrict__ bbf,
    const unsigned short* __restrict__ Wlin2, const float* __restrict__ b1v,
    const float* __restrict__ b2v, float* __restrict__ out)
{
    const int row0  = blockIdx.x * 2;
    const int batch = row0 >> 7;
    const int t     = threadIdx.x;
    const int w  = t >> 6, l = t & 63;
    const int lg = l >> 4, li = l & 15;

    __shared__ unsigned short Tf[2 * 4 * 64 * 8];    // 8 KB
    __shared__ __align__(16) float stg[STAGE_N];     // 25.5 KB (one row)
    __shared__ float al[2][DH];

    #pragma unroll
    for (int s = 0; s < 8; ++s)
        ((unsigned int*)Tf)[t + s * 256] = 0u;       // pads k=51..63 stay 0
    if (t < 2 * DH) al[t >> 5][t & 31] = a_ws[row0 * DH + t];
    __syncthreads();

    // ---- phase 1: T GEMV (uint4-packed Wlin2) ----
    {
        float tacc0[7], tacc1[7];
        int fidx[7];
        bool val[7];
        #pragma unroll
        for (int s = 0; s < 7; ++s) {
            int o = t + s * 256;
            val[s] = (o < WCAT);
            int oo = val[s] ? o : 0;
            int d, k;
            if (oo < 672) { d = oo / 21; k = oo % 21; }
            else { int o2 = oo - 672; d = o2 / 30; k = 21 + o2 % 30; }
            fidx[s] = (((k >> 4) * 64 + ((k & 15) | ((d >> 3) << 4))) << 3) | (d & 7);
            tacc0[s] = 0.f; tacc1[s] = 0.f;
        }
        const uint4* wbase = ((const uint4*)Wlin2) + t;
        #pragma unroll 4
        for (int c = 0; c < DH; ++c) {
            float ac0 = al[0][c], ac1 = al[1][c];
            uint4 wq = wbase[c * 256];
            float wv[7];
            wv[0] = __uint_as_float(wq.x << 16);
            wv[1] = __uint_as_float(wq.x & 0xffff0000u);
            wv[2] = __uint_as_float(wq.y << 16);
            wv[3] = __uint_as_float(wq.y & 0xffff0000u);
            wv[4] = __uint_as_float(wq.z << 16);
            wv[5] = __uint_as_float(wq.z & 0xffff0000u);
            wv[6] = __uint_as_float(wq.w << 16);
            #pragma unroll
            for (int s = 0; s < 7; ++s) {
                tacc0[s] = fmaf(ac0, wv[s], tacc0[s]);
                tacc1[s] = fmaf(ac1, wv[s], tacc1[s]);
            }
        }
        #pragma unroll
        for (int s = 0; s < 7; ++s) {
            if (val[s]) {
                Tf[fidx[s]]        = f2bf(tacc0[s]);
                Tf[2048 + fidx[s]] = f2bf(tacc1[s]);
            }
        }
    }
    __syncthreads();

    // ---- phase 2/3: per-row MFMA + stage + copyout (verified) ----
    const int r  = w >> 1;            // wave's row within pair
    const int mh = w & 1;             // m-half

    bf16x8 afr[4], bfr[4];
    #pragma unroll
    for (int i = 0; i < 4; ++i)
        afr[i] = ((const bf16x8*)bbf)[batch * 512 + (mh * 4 + i) * 64 + l];
    #pragma unroll
    for (int kt = 0; kt < 4; ++kt)
        bfr[kt] = ((const bf16x8*)Tf)[(r * 4 + kt) * 64 + l];

    float bias[4];
    #pragma unroll
    for (int kt = 0; kt < 4; ++kt) {
        int k = kt * 16 + li;
        bias[kt] = (k < K1) ? b1v[k] : (k < KT ? b2v[k - K1] : 0.f);
    }

    #pragma unroll
    for (int rr = 0; rr < 2; ++rr) {
        if (r == rr) {
            #pragma unroll
            for (int i = 0; i < 4; ++i) {
                const int mbase = (mh * 4 + i) * 16 + lg * 4;
                #pragma unroll
                for (int kt = 0; kt < 4; ++kt) {
                    f32x4 acc = __builtin_amdgcn_mfma_f32_16x16x32_bf16(
                        afr[i], bfr[kt], (f32x4){0.f, 0.f, 0.f, 0.f}, 0, 0, 0);
                    const int k = kt * 16 + li;
                    if (k < K1) {
                        #pragma unroll
                        for (int q = 0; q < 4; ++q)
                            stg[(mbase + q) * K1 + k] = acc[q] + bias[kt];
                    } else if (k < KT) {
                        #pragma unroll
                        for (int q = 0; q < 4; ++q)
                            stg[OUT1_ROW + (mbase + q) * K2 + (k - K1)] = acc[q] + bias[kt];
                    }
                }
            }
        }
        __syncthreads();

        const int row = row0 + rr;
        float* o1 = out + (size_t)row * OUT1_ROW;
        float* o2 = out + (size_t)ROWS * OUT1_ROW + (size_t)row * OUT2_ROW;
        const float4* s1 = (const float4*)stg;
        const float4* s2 = (const float4*)(stg + OUT1_ROW);
        for (int i4 = t; i4 < OUT1_ROW / 4; i4 += 256)
            ((float4*)o1)[i4] = s1[i4];
        for (int i4 = t; i4 < OUT2_ROW / 4; i4 += 256)
            ((float4*)o2)[i4] = s2[i4];
        if (rr == 0) __syncthreads();   // stg reused by row 1
    }
}

extern "C" void kernel_launch(void* const* d_in, const int* in_sizes, int n_in,
                              void* d_out, int out_size, void* d_ws, size_t ws_size,
                              hipStream_t stream) {
    const float* z    = (const float*)d_in[0];
    const float* W_in = (const float*)d_in[1];
    const float* b_in = (const float*)d_in[2];
    const float* ln_g = (const float*)d_in[3];
    const float* ln_b = (const float*)d_in[4];
    const float* W1   = (const float*)d_in[5];
    const float* b1   = (const float*)d_in[6];
    const float* W2   = (const float*)d_in[7];
    const float* b2   = (const float*)d_in[8];
    float* out = (float*)d_out;

    float*          a_ws  = (float*)d_ws;                    // 32768 f32 (128 KB)
    unsigned short* bbf   = (unsigned short*)(a_ws + 32768); // 32768 hw (64 KB)
    unsigned short* Wlin2 = bbf + 32768;                     // 65536 hw (128 KB)

    ln_wprep_kernel<<<256, 256, 0, stream>>>(z, W_in, b_in, ln_g, ln_b,
                                             W1, W2, a_ws, bbf, Wlin2);
    pair_kernel<<<ROWS / 2, 256, 0, stream>>>(a_ws, bbf, Wlin2, b1, b2, out);
}